// Round 1
// 55.405 us; speedup vs baseline: 1.0411x; 1.0411x over previous
//
#include <hip/hip_runtime.h>

typedef __attribute__((ext_vector_type(8))) short bf16x8;
typedef __attribute__((ext_vector_type(4))) float f32x4;
typedef unsigned int u32;
typedef unsigned short u16;

#define BB 8192
#define DD 128
#define CC 64
#define NSLICE 16
#define SLICE_COLS 512       // 8192/16
#define NTILES 8             // 512/64

typedef __attribute__((address_space(1))) void gvoid;
typedef __attribute__((address_space(3))) void lvoid;

static __device__ __forceinline__ u16 f2bf(float x) {
    u32 u = __float_as_uint(x);
    return (u16)((u + 0x7FFFu + ((u >> 16) & 1u)) >> 16);
}
static __device__ __forceinline__ u32 umaxu(u32 a, u32 b) { return a > b ? a : b; }
static __device__ __forceinline__ u32 uminu(u32 a, u32 b) { return a < b ? a : b; }

// direct global->LDS DMA, 16B per lane; dest is wave-uniform base + lane*16
static __device__ __forceinline__ void gload16(const void* g, void* l) {
    __builtin_amdgcn_global_load_lds((const gvoid*)g, (lvoid*)l, 16, 0, 0);
}

// ---------------- kernel 0: row squared norms (fp32 exact) + bf16 convert ----------------
__global__ __launch_bounds__(256) void k_prep(const float* __restrict__ E,
                                              float* __restrict__ sq,
                                              u16* __restrict__ Ebf) {
    int row = blockIdx.x * 4 + (threadIdx.x >> 6);
    int l   = threadIdx.x & 63;
    float2 v = *reinterpret_cast<const float2*>(E + (size_t)row * DD + l * 2);
    ushort2 bv = make_ushort2(f2bf(v.x), f2bf(v.y));
    *reinterpret_cast<ushort2*>(Ebf + (size_t)row * DD + l * 2) = bv;
    float s = v.x * v.x + v.y * v.y;
    #pragma unroll
    for (int m = 32; m; m >>= 1) s += __shfl_xor(s, m);
    if (l == 0) sq[row] = s;
}

// ---------------- kernel 1: bf16 MFMA pairwise + packed-key batch-hard mining ----------------
// Grid: (32, 16). Block: 256 thr = 4 waves; wave w owns rows rowW..rowW+63.
// Slice = 512 cols = 8 tiles of 64. Double-buffered global_load_lds staging
// (pre-swizzled source, linear LDS dest -> identical XOR-swizzled image),
// counted vmcnt(4) + raw barriers: no full drains in the main loop.
__global__ __launch_bounds__(256, 2) void k_mine(const u16* __restrict__ Ebf,
                                                 const float* __restrict__ sq,
                                                 const int* __restrict__ lab,
                                                 u32* __restrict__ pmax,
                                                 u32* __restrict__ pmin) {
    __shared__ uint4 Bt4[2][1024];               // 2 x 16 KB B tiles

    const int tid = threadIdx.x;
    const int l   = tid & 63;
    const int w   = tid >> 6;
    const int l15 = l & 15;
    const int l4  = l >> 4;
    const int rowW = blockIdx.x * 256 + w * 64;
    const int col0 = blockIdx.y * SLICE_COLS;

    // ---- A fragments in registers: a[rb][kk], lane holds row (rowW+rb*16+l15), k = kk*32 + l4*8 .. +8 ----
    bf16x8 a[4][4];
    #pragma unroll
    for (int rb = 0; rb < 4; ++rb)
        #pragma unroll
        for (int kk = 0; kk < 4; ++kk)
            a[rb][kk] = *reinterpret_cast<const bf16x8*>(
                Ebf + (size_t)(rowW + rb * 16 + l15) * DD + kk * 32 + l4 * 8);

    // row labels for this lane's 16 accumulator row-slots: row = rowW + rb*16 + l4*4 + e
    int labr[4][4];
    #pragma unroll
    for (int rb = 0; rb < 4; ++rb)
        #pragma unroll
        for (int e = 0; e < 4; ++e)
            labr[rb][e] = lab[rowW + rb * 16 + l4 * 4 + e];

    u32 kmax[4][4], kmin[4][4];
    #pragma unroll
    for (int rb = 0; rb < 4; ++rb)
        #pragma unroll
        for (int e = 0; e < 4; ++e) { kmax[rb][e] = 0u; kmin[rb][e] = 0xFFFFFFFFu; }

    // staging coords (same thread->(r,sx) map as the old reg-staging path)
    const int srow = tid >> 4;            // 0..15
    const int sx   = (tid & 15) * 16;     // 0..240

    // DMA stage of tile tt into buffer bufi. LDS dest linear (tid*16 within 4KB
    // rounds); global source pre-swizzled so LDS[r*256 + c] = G[(colT+r)*256 + (c ^ swz(r))],
    // identical to the previous ds_write image.
    auto stage = [&](int bufi, int tt) {
        const char* gs = (const char*)Ebf + (size_t)(col0 + tt * 64) * 256;
        char* lb = (char*)&Bt4[bufi][0] + w * 1024;   // wave-uniform base
        #pragma unroll
        for (int rd = 0; rd < 4; ++rd) {
            int r = rd * 16 + srow;
            gload16(gs + r * 256 + (sx ^ ((r & 7) << 4)), lb + rd * 4096);
        }
    };

    stage(0, 0);

    for (int t = 0; t < NTILES; ++t) {
        if (t + 1 < NTILES) {
            stage((t + 1) & 1, t + 1);                       // 4 loads stay in flight
            asm volatile("s_waitcnt vmcnt(4)" ::: "memory"); // wait tile t only
        } else {
            asm volatile("s_waitcnt vmcnt(0)" ::: "memory");
        }
        __builtin_amdgcn_s_barrier();       // tile t visible to all waves
        asm volatile("" ::: "memory");      // keep ds_reads below the barrier

        const char* Bt = (const char*)&Bt4[t & 1][0];
        const int colT = col0 + t * 64;

        // column metadata for this lane: col = colT + cb*16 + l15
        float cbias[4]; int labc[4]; u32 jx[4], jn[4];
        #pragma unroll
        for (int cb = 0; cb < 4; ++cb) {
            int gj = colT + cb * 16 + l15;
            cbias[cb] = sq[gj] + 1024.0f;    // bias keeps key value strictly positive
            labc[cb]  = lab[gj];
            jn[cb] = (u32)gj;
            jx[cb] = (u32)(8191 - gj);
        }

        const bool isdiag = (rowW == colT);

        auto tilebody = [&](bool dg) {
            #pragma unroll
            for (int cb = 0; cb < 4; ++cb) {
                // B fragments from swizzled LDS: lane row = cb*16+l15, k = kk*32 + l4*8
                bf16x8 b[4];
                #pragma unroll
                for (int kk = 0; kk < 4; ++kk) {
                    int r = cb * 16 + l15;
                    b[kk] = *reinterpret_cast<const bf16x8*>(
                        Bt + r * 256 + ((kk * 64 + l4 * 16) ^ ((r & 7) << 4)));
                }
                f32x4 acc[4];
                #pragma unroll
                for (int rb = 0; rb < 4; ++rb) acc[rb] = (f32x4){0.f, 0.f, 0.f, 0.f};
                #pragma unroll
                for (int kk = 0; kk < 4; ++kk)
                    #pragma unroll
                    for (int rb = 0; rb < 4; ++rb)
                        acc[rb] = __builtin_amdgcn_mfma_f32_16x16x32_bf16(
                            a[rb][kk], b[kk], acc[rb], 0, 0, 0);

                // mining epilogue: val = (sq_j + 1024) - 2*ip ; key = high-bits(val) | idx
                #pragma unroll
                for (int rb = 0; rb < 4; ++rb)
                    #pragma unroll
                    for (int e = 0; e < 4; ++e) {
                        float val = fmaf(acc[rb][e], -2.0f, cbias[cb]);
                        u32 base = __float_as_uint(val) & 0xFFFFE000u;
                        bool eq = (labr[rb][e] == labc[cb]);
                        bool selfhit = dg && ((rb * 16 + l4 * 4 + e) == (cb * 16 + l15));
                        u32 cx = (eq && !selfhit) ? (base | jx[cb]) : 0u;
                        u32 cn = eq ? 0xFFFFFFFFu : (base | jn[cb]);
                        kmax[rb][e] = umaxu(kmax[rb][e], cx);
                        kmin[rb][e] = uminu(kmin[rb][e], cn);
                    }
            }
        };
        if (isdiag) tilebody(true); else tilebody(false);

        asm volatile("" ::: "memory");      // keep ds_reads above the barrier
        __builtin_amdgcn_s_barrier();       // all waves done reading buf[t&1]
    }

    // cross-lane reduce over the 16 l15 lanes of each l4 group (keys already tie-break-correct)
    #pragma unroll
    for (int rb = 0; rb < 4; ++rb)
        #pragma unroll
        for (int e = 0; e < 4; ++e) {
            u32 kx = kmax[rb][e], kn = kmin[rb][e];
            #pragma unroll
            for (int m = 1; m < 16; m <<= 1) {
                u32 ox = (u32)__shfl_xor((int)kx, m); kx = umaxu(kx, ox);
                u32 on = (u32)__shfl_xor((int)kn, m); kn = uminu(kn, on);
            }
            if (l15 == 0) {
                int row = rowW + rb * 16 + l4 * 4 + e;
                pmax[(size_t)blockIdx.y * BB + row] = kx;
                pmin[(size_t)blockIdx.y * BB + row] = kn;
            }
        }
}

// ---------------- kernel 2: combine slices + exact fp32 loss per row ----------------
__global__ __launch_bounds__(256) void k_finalize(const float* __restrict__ E,
                                                  const float* __restrict__ M,
                                                  const int* __restrict__ lab,
                                                  const u32* __restrict__ pmax,
                                                  const u32* __restrict__ pmin,
                                                  float* __restrict__ loss,
                                                  float* __restrict__ validf) {
    int row = blockIdx.x * 4 + (threadIdx.x >> 6);
    int l   = threadIdx.x & 63;
    int l15 = l & 15;

    u32 kx = pmax[(size_t)l15 * BB + row];
    u32 kn = pmin[(size_t)l15 * BB + row];
    #pragma unroll
    for (int m = 1; m < 16; m <<= 1) {
        u32 ox = (u32)__shfl_xor((int)kx, m); kx = umaxu(kx, ox);
        u32 on = (u32)__shfl_xor((int)kn, m); kn = uminu(kn, on);
    }
    bool valid = (kx != 0u) && (kn != 0xFFFFFFFFu);
    int hp = 8191 - (int)(kx & 0x1FFFu);
    int hn = (int)(kn & 0x1FFFu);

    float2 ei = *reinterpret_cast<const float2*>(E + (size_t)row * DD + l * 2);
    float2 ep = *reinterpret_cast<const float2*>(E + (size_t)hp  * DD + l * 2);
    float2 en = *reinterpret_cast<const float2*>(E + (size_t)hn  * DD + l * 2);
    float dx = ei.x - ep.x, dy = ei.y - ep.y;
    float sap = dx * dx + dy * dy;
    dx = ei.x - en.x; dy = ei.y - en.y;
    float san = dx * dx + dy * dy;
    #pragma unroll
    for (int m = 32; m; m >>= 1) {
        sap += __shfl_xor(sap, m);
        san += __shfl_xor(san, m);
    }
    if (l == 0) {
        float dap = sqrtf(sap), dan = sqrtf(san);
        float mg = M[lab[row] * CC + lab[hn]];
        float lo = fmaxf(dap - dan + mg, 0.0f);
        loss[row]   = valid ? lo : 0.0f;
        validf[row] = valid ? 1.0f : 0.0f;
    }
}

// ---------------- kernel 3: scalar reduction ----------------
__global__ __launch_bounds__(256) void k_reduce(const float* __restrict__ loss,
                                                const float* __restrict__ validf,
                                                float* __restrict__ out) {
    __shared__ float sl[256], sv[256];
    int tid = threadIdx.x;
    float a = 0.f, b = 0.f;
    for (int i = tid; i < BB; i += 256) { a += loss[i]; b += validf[i]; }
    sl[tid] = a; sv[tid] = b;
    __syncthreads();
    for (int s = 128; s; s >>= 1) {
        if (tid < s) { sl[tid] += sl[tid + s]; sv[tid] += sv[tid + s]; }
        __syncthreads();
    }
    if (tid == 0) out[0] = sl[0] / fmaxf(sv[0], 1.0f);
}

extern "C" void kernel_launch(void* const* d_in, const int* in_sizes, int n_in,
                              void* d_out, int out_size, void* d_ws, size_t ws_size,
                              hipStream_t stream) {
    const float* E   = (const float*)d_in[0];   // [B][D] fp32
    const float* M   = (const float*)d_in[1];   // [C][C] fp32
    const int*   lab = (const int*)d_in[2];     // [B]
    float* out = (float*)d_out;

    char* ws = (char*)d_ws;
    u16*   Ebf  = (u16*)ws;        ws += (size_t)BB * DD * 2;     // 2 MB
    float* sq   = (float*)ws;      ws += (size_t)BB * 4;
    u32*   pmax = (u32*)ws;        ws += (size_t)NSLICE * BB * 4; // 512 KB
    u32*   pmin = (u32*)ws;        ws += (size_t)NSLICE * BB * 4; // 512 KB
    float* loss = (float*)ws;      ws += (size_t)BB * 4;
    float* valf = (float*)ws;      ws += (size_t)BB * 4;

    k_prep<<<BB / 4, 256, 0, stream>>>(E, sq, Ebf);
    k_mine<<<dim3(BB / 256, NSLICE), 256, 0, stream>>>(Ebf, sq, lab, pmax, pmin);
    k_finalize<<<BB / 4, 256, 0, stream>>>(E, M, lab, pmax, pmin, loss, valf);
    k_reduce<<<1, 256, 0, stream>>>(loss, valf, out);
}

// Round 2
// 54.528 us; speedup vs baseline: 1.0578x; 1.0161x over previous
//
#include <hip/hip_runtime.h>

typedef __attribute__((ext_vector_type(8))) short bf16x8;
typedef __attribute__((ext_vector_type(4))) float f32x4;
typedef unsigned int u32;
typedef unsigned short u16;

#define BB 8192
#define DD 128
#define CC 64
#define NSLICE 16
#define SLICE_COLS 512       // 8192/16
#define NTILES 8             // 512/64

typedef __attribute__((address_space(1))) void gvoid;
typedef __attribute__((address_space(3))) void lvoid;

static __device__ __forceinline__ u16 f2bf(float x) {
    u32 u = __float_as_uint(x);
    return (u16)((u + 0x7FFFu + ((u >> 16) & 1u)) >> 16);
}
static __device__ __forceinline__ u32 umaxu(u32 a, u32 b) { return a > b ? a : b; }
static __device__ __forceinline__ u32 uminu(u32 a, u32 b) { return a < b ? a : b; }

// (val & mask) | (idx & ~mask) in one VALU op; mask uniform -> SGPR
static __device__ __forceinline__ u32 bfi_key(u32 mask, u32 val, u32 idx) {
    u32 r;
    asm("v_bfi_b32 %0, %1, %2, %3" : "=v"(r) : "s"(mask), "v"(val), "v"(idx));
    return r;
}

// direct global->LDS DMA, 16B per lane; dest is wave-uniform base + lane*16
static __device__ __forceinline__ void gload16(const void* g, void* l) {
    __builtin_amdgcn_global_load_lds((const gvoid*)g, (lvoid*)l, 16, 0, 0);
}

// ---------------- kernel 0: row squared norms (fp32 exact) + bf16 convert ----------------
__global__ __launch_bounds__(256) void k_prep(const float* __restrict__ E,
                                              float* __restrict__ sq,
                                              u16* __restrict__ Ebf) {
    int row = blockIdx.x * 4 + (threadIdx.x >> 6);
    int l   = threadIdx.x & 63;
    float2 v = *reinterpret_cast<const float2*>(E + (size_t)row * DD + l * 2);
    ushort2 bv = make_ushort2(f2bf(v.x), f2bf(v.y));
    *reinterpret_cast<ushort2*>(Ebf + (size_t)row * DD + l * 2) = bv;
    float s = v.x * v.x + v.y * v.y;
    #pragma unroll
    for (int m = 32; m; m >>= 1) s += __shfl_xor(s, m);
    if (l == 0) sq[row] = s;
}

// ---------------- kernel 1: bf16 MFMA pairwise + packed-key batch-hard mining ----------------
// Grid: (32, 16). Block: 256 thr = 4 waves; wave w owns rows rowW..rowW+63.
// Slice = 512 cols = 8 tiles of 64. 3-deep global_load_lds ring
// (pre-swizzled source, linear LDS dest), counted vmcnt(4), ONE barrier per tile.
__global__ __launch_bounds__(256, 2) void k_mine(const u16* __restrict__ Ebf,
                                                 const float* __restrict__ sq,
                                                 const int* __restrict__ lab,
                                                 u32* __restrict__ pmax,
                                                 u32* __restrict__ pmin) {
    __shared__ uint4 Bt4[3][1024];               // 3 x 16 KB B tiles (ring)

    const int tid = threadIdx.x;
    const int l   = tid & 63;
    const int w   = tid >> 6;
    const int l15 = l & 15;
    const int l4  = l >> 4;
    const int rowW = blockIdx.x * 256 + w * 64;
    const int col0 = blockIdx.y * SLICE_COLS;

    // ---- A fragments in registers: a[rb][kk], lane holds row (rowW+rb*16+l15), k = kk*32 + l4*8 .. +8 ----
    bf16x8 a[4][4];
    #pragma unroll
    for (int rb = 0; rb < 4; ++rb)
        #pragma unroll
        for (int kk = 0; kk < 4; ++kk)
            a[rb][kk] = *reinterpret_cast<const bf16x8*>(
                Ebf + (size_t)(rowW + rb * 16 + l15) * DD + kk * 32 + l4 * 8);

    // row labels for this lane's 16 accumulator row-slots: row = rowW + rb*16 + l4*4 + e
    int labr[4][4];
    #pragma unroll
    for (int rb = 0; rb < 4; ++rb)
        #pragma unroll
        for (int e = 0; e < 4; ++e)
            labr[rb][e] = lab[rowW + rb * 16 + l4 * 4 + e];

    u32 kmax[4][4], kmin[4][4];
    #pragma unroll
    for (int rb = 0; rb < 4; ++rb)
        #pragma unroll
        for (int e = 0; e < 4; ++e) { kmax[rb][e] = 0u; kmin[rb][e] = 0xFFFFFFFFu; }

    // hoisted, tile-invariant swizzled LDS offsets for the b-fragment reads
    u32 boff[4][4];
    #pragma unroll
    for (int cb = 0; cb < 4; ++cb)
        #pragma unroll
        for (int kk = 0; kk < 4; ++kk) {
            int r = cb * 16 + l15;
            boff[cb][kk] = (u32)(r * 256 + ((kk * 64 + l4 * 16) ^ ((r & 7) << 4)));
        }

    // staging coords (constant across tiles)
    const int srow = tid >> 4;            // 0..15
    const int sx   = (tid & 15) * 16;     // 0..240

    // DMA stage of tile tt into ring slot bufi. LDS dest linear; global source
    // pre-swizzled so LDS[r*256 + c] = G[(colT+r)*256 + (c ^ swz(r))].
    auto stage = [&](int bufi, int tt) {
        const char* gs = (const char*)Ebf + (size_t)(col0 + tt * 64) * 256;
        char* lb = (char*)&Bt4[bufi][0] + w * 1024;   // wave-uniform base
        #pragma unroll
        for (int rd = 0; rd < 4; ++rd) {
            int r = rd * 16 + srow;
            gload16(gs + r * 256 + (sx ^ ((r & 7) << 4)), lb + rd * 4096);
        }
    };

    stage(0, 0);
    const u32 HM = 0xFFFFE000u;
    int cur = 0;

    for (int t = 0; t < NTILES; ++t) {
        int nxt = cur + 1; if (nxt == 3) nxt = 0;
        if (t + 1 < NTILES) {
            stage(nxt, t + 1);                               // 4 loads stay in flight
            asm volatile("s_waitcnt vmcnt(4)" ::: "memory"); // own stage(t) landed
        } else {
            asm volatile("s_waitcnt vmcnt(0)" ::: "memory");
        }
        __builtin_amdgcn_s_barrier();       // all waves' stage(t) landed; buf reuse safe
        asm volatile("" ::: "memory");      // keep ds_reads below the barrier

        const char* Bt = (const char*)&Bt4[cur][0];
        const int colT = col0 + t * 64;

        // column metadata for this lane: col = colT + cb*16 + l15
        float cbias[4]; int labc[4]; u32 jx[4], jn[4];
        #pragma unroll
        for (int cb = 0; cb < 4; ++cb) {
            int gj = colT + cb * 16 + l15;
            cbias[cb] = sq[gj] + 1024.0f;    // bias keeps key value strictly positive
            labc[cb]  = lab[gj];
            jn[cb] = (u32)gj & 0x1FFFu;
            jx[cb] = (u32)(8191 - gj) & 0x1FFFu;
        }

        const bool isdiag = (rowW == colT);

        auto tilebody = [&](bool dg) {
            #pragma unroll
            for (int cb = 0; cb < 4; ++cb) {
                // B fragments from swizzled LDS: lane row = cb*16+l15, k = kk*32 + l4*8
                bf16x8 b[4];
                #pragma unroll
                for (int kk = 0; kk < 4; ++kk)
                    b[kk] = *reinterpret_cast<const bf16x8*>(Bt + boff[cb][kk]);
                f32x4 acc[4];
                #pragma unroll
                for (int rb = 0; rb < 4; ++rb) acc[rb] = (f32x4){0.f, 0.f, 0.f, 0.f};
                #pragma unroll
                for (int kk = 0; kk < 4; ++kk)
                    #pragma unroll
                    for (int rb = 0; rb < 4; ++rb)
                        acc[rb] = __builtin_amdgcn_mfma_f32_16x16x32_bf16(
                            a[rb][kk], b[kk], acc[rb], 0, 0, 0);

                // mining epilogue: val = (sq_j + 1024) - 2*ip ; key = bfi(val, idx)
                #pragma unroll
                for (int rb = 0; rb < 4; ++rb)
                    #pragma unroll
                    for (int e = 0; e < 4; ++e) {
                        float val = fmaf(acc[rb][e], -2.0f, cbias[cb]);
                        u32 vb = __float_as_uint(val);
                        u32 keyx = bfi_key(HM, vb, jx[cb]);
                        u32 keyn = bfi_key(HM, vb, jn[cb]);
                        bool eq = (labr[rb][e] == labc[cb]);
                        bool selfhit = dg && ((rb * 16 + l4 * 4 + e) == (cb * 16 + l15));
                        u32 cx = (eq && !selfhit) ? keyx : 0u;
                        u32 cn = eq ? 0xFFFFFFFFu : keyn;
                        kmax[rb][e] = umaxu(kmax[rb][e], cx);
                        kmin[rb][e] = uminu(kmin[rb][e], cn);
                    }
            }
        };
        if (isdiag) tilebody(true); else tilebody(false);

        cur = nxt;
    }

    // cross-lane reduce over the 16 l15 lanes of each l4 group (keys already tie-break-correct)
    #pragma unroll
    for (int rb = 0; rb < 4; ++rb)
        #pragma unroll
        for (int e = 0; e < 4; ++e) {
            u32 kx = kmax[rb][e], kn = kmin[rb][e];
            #pragma unroll
            for (int m = 1; m < 16; m <<= 1) {
                u32 ox = (u32)__shfl_xor((int)kx, m); kx = umaxu(kx, ox);
                u32 on = (u32)__shfl_xor((int)kn, m); kn = uminu(kn, on);
            }
            if (l15 == 0) {
                int row = rowW + rb * 16 + l4 * 4 + e;
                pmax[(size_t)blockIdx.y * BB + row] = kx;
                pmin[(size_t)blockIdx.y * BB + row] = kn;
            }
        }
}

// ---------------- kernel 2: combine slices + exact fp32 loss per row ----------------
__global__ __launch_bounds__(256) void k_finalize(const float* __restrict__ E,
                                                  const float* __restrict__ M,
                                                  const int* __restrict__ lab,
                                                  const u32* __restrict__ pmax,
                                                  const u32* __restrict__ pmin,
                                                  float* __restrict__ loss,
                                                  float* __restrict__ validf) {
    int row = blockIdx.x * 4 + (threadIdx.x >> 6);
    int l   = threadIdx.x & 63;
    int l15 = l & 15;

    u32 kx = pmax[(size_t)l15 * BB + row];
    u32 kn = pmin[(size_t)l15 * BB + row];
    #pragma unroll
    for (int m = 1; m < 16; m <<= 1) {
        u32 ox = (u32)__shfl_xor((int)kx, m); kx = umaxu(kx, ox);
        u32 on = (u32)__shfl_xor((int)kn, m); kn = uminu(kn, on);
    }
    bool valid = (kx != 0u) && (kn != 0xFFFFFFFFu);
    int hp = 8191 - (int)(kx & 0x1FFFu);
    int hn = (int)(kn & 0x1FFFu);

    float2 ei = *reinterpret_cast<const float2*>(E + (size_t)row * DD + l * 2);
    float2 ep = *reinterpret_cast<const float2*>(E + (size_t)hp  * DD + l * 2);
    float2 en = *reinterpret_cast<const float2*>(E + (size_t)hn  * DD + l * 2);
    float dx = ei.x - ep.x, dy = ei.y - ep.y;
    float sap = dx * dx + dy * dy;
    dx = ei.x - en.x; dy = ei.y - en.y;
    float san = dx * dx + dy * dy;
    #pragma unroll
    for (int m = 32; m; m >>= 1) {
        sap += __shfl_xor(sap, m);
        san += __shfl_xor(san, m);
    }
    if (l == 0) {
        float dap = sqrtf(sap), dan = sqrtf(san);
        float mg = M[lab[row] * CC + lab[hn]];
        float lo = fmaxf(dap - dan + mg, 0.0f);
        loss[row]   = valid ? lo : 0.0f;
        validf[row] = valid ? 1.0f : 0.0f;
    }
}

// ---------------- kernel 3: scalar reduction (order unchanged: absmax must stay 0) ----------------
__global__ __launch_bounds__(256) void k_reduce(const float* __restrict__ loss,
                                                const float* __restrict__ validf,
                                                float* __restrict__ out) {
    __shared__ float sl[256], sv[256];
    int tid = threadIdx.x;
    float a = 0.f, b = 0.f;
    for (int i = tid; i < BB; i += 256) { a += loss[i]; b += validf[i]; }
    sl[tid] = a; sv[tid] = b;
    __syncthreads();
    for (int s = 128; s; s >>= 1) {
        if (tid < s) { sl[tid] += sl[tid + s]; sv[tid] += sv[tid + s]; }
        __syncthreads();
    }
    if (tid == 0) out[0] = sl[0] / fmaxf(sv[0], 1.0f);
}

extern "C" void kernel_launch(void* const* d_in, const int* in_sizes, int n_in,
                              void* d_out, int out_size, void* d_ws, size_t ws_size,
                              hipStream_t stream) {
    const float* E   = (const float*)d_in[0];   // [B][D] fp32
    const float* M   = (const float*)d_in[1];   // [C][C] fp32
    const int*   lab = (const int*)d_in[2];     // [B]
    float* out = (float*)d_out;

    char* ws = (char*)d_ws;
    u16*   Ebf  = (u16*)ws;        ws += (size_t)BB * DD * 2;     // 2 MB
    float* sq   = (float*)ws;      ws += (size_t)BB * 4;
    u32*   pmax = (u32*)ws;        ws += (size_t)NSLICE * BB * 4; // 512 KB
    u32*   pmin = (u32*)ws;        ws += (size_t)NSLICE * BB * 4; // 512 KB
    float* loss = (float*)ws;      ws += (size_t)BB * 4;
    float* valf = (float*)ws;      ws += (size_t)BB * 4;

    k_prep<<<BB / 4, 256, 0, stream>>>(E, sq, Ebf);
    k_mine<<<dim3(BB / 256, NSLICE), 256, 0, stream>>>(Ebf, sq, lab, pmax, pmin);
    k_finalize<<<BB / 4, 256, 0, stream>>>(E, M, lab, pmax, pmin, loss, valf);
    k_reduce<<<1, 256, 0, stream>>>(loss, valf, out);
}